// Round 1
// baseline (747.873 us; speedup 1.0000x reference)
//
#include <hip/hip_runtime.h>
#include <math.h>

#define NPTS 32768
#define NTYPES 4
#define PER_TYPE 8192
#define HIST 32
#define UD 128
#define XT_STRIDE 68   // pad 128-row tiles: 68*4B=272B row pitch, 16B-aligned, breaks pow2 bank stride

// ws layout (float offsets):
//   q     [32768][128]      @ 0
//   qk    [32768][128]      @ 4194304
//   raw   [32768][32]       @ 8388608
//   Mbits [128] (uint)      @ 9437184
//   S     [128]             @ 9437312
//   kT    [4][128][128]     @ 9437440   (k_w transposed per type)
//   wvf   [4][128][128]     @ 9502976   (v_w @ fc_w per type)
// total 9568512 floats = 38.3 MB

__device__ __forceinline__ unsigned fkey(float x) {
    unsigned b = __float_as_uint(x);
    return (b & 0x80000000u) ? ~b : (b | 0x80000000u);
}
__device__ __forceinline__ float funkey(unsigned k) {
    unsigned b = (k & 0x80000000u) ? (k & 0x7fffffffu) : ~k;
    return __uint_as_float(b);
}

// ---------------- prep: kT = k_w^T, wvf = v_w @ fc_w, zero softmax stats -------------
__global__ __launch_bounds__(128) void prep_kernel(
    const float* __restrict__ k_w, const float* __restrict__ v_w,
    const float* __restrict__ fc_w, float* __restrict__ kT,
    float* __restrict__ wvf, unsigned* __restrict__ Mbits, float* __restrict__ S)
{
    int r = blockIdx.x;   // 0..127 (row of output)
    int t = blockIdx.y;   // type
    int u = threadIdx.x;  // 0..127 (col)
    // kT[t][r][u] = k_w[t][u][r]
    kT[(t * UD + r) * UD + u] = k_w[(t * UD + u) * UD + r];
    // wvf[t][r][u] = sum_m v_w[t][r][m] * fc_w[t][m][u]
    float acc = 0.f;
    const float* vrow = v_w + (t * UD + r) * UD;
    const float* fb = fc_w + t * UD * UD;
    #pragma unroll 8
    for (int m = 0; m < UD; ++m)
        acc = fmaf(vrow[m], fb[m * UD + u], acc);
    wvf[(t * UD + r) * UD + u] = acc;
    if (r == 0 && t == 0) { Mbits[u] = 0u; S[u] = 0.f; }
}

// ---------------- q = x[idx] @ q_w ; qk = q @ k_w^T  (per 64-entity tile) ------------
__global__ __launch_bounds__(256) void qqk_kernel(
    const float* __restrict__ x, const int* __restrict__ idx,
    const float* __restrict__ q_w, const float* __restrict__ kT,
    float* __restrict__ q_out, float* __restrict__ qk_out)
{
    __shared__ float xT[UD * XT_STRIDE];  // [e][ent], padded
    __shared__ float qT[UD * XT_STRIDE];  // [c][ent], padded
    __shared__ int srow[64];
    int tx = threadIdx.x;
    int bn = blockIdx.x;      // 0..127 -> 64 entities
    int t  = blockIdx.y;
    int n0 = bn * 64;

    if (tx < 64) srow[tx] = idx[t * PER_TYPE + n0 + tx];
    __syncthreads();

    // load x transposed into LDS: xT[e][ent]
    {
        int e = tx & 127;
        int half = tx >> 7;
        for (int i = 0; i < 32; ++i) {
            int ent = half * 32 + i;
            xT[e * XT_STRIDE + ent] = x[(size_t)srow[ent] * UD + e];
        }
    }
    __syncthreads();

    const int c4 = (tx & 31) * 4;  // 4 output cols
    const int eg = tx >> 5;        // 0..7 -> 8 entities eg*8..eg*8+7
    float acc[8][4];

    // phase 1: q[ent][c] = sum_e xT[e][ent] * q_w[e][c]
    #pragma unroll
    for (int i = 0; i < 8; ++i)
        #pragma unroll
        for (int j = 0; j < 4; ++j) acc[i][j] = 0.f;
    {
        const float* qw = q_w + t * UD * UD;
        for (int e = 0; e < UD; ++e) {
            float4 w = *(const float4*)(qw + e * UD + c4);
            const float* xr = &xT[e * XT_STRIDE + eg * 8];
            float4 a0 = *(const float4*)(xr);
            float4 a1 = *(const float4*)(xr + 4);
            float av[8] = {a0.x, a0.y, a0.z, a0.w, a1.x, a1.y, a1.z, a1.w};
            #pragma unroll
            for (int i = 0; i < 8; ++i) {
                acc[i][0] = fmaf(av[i], w.x, acc[i][0]);
                acc[i][1] = fmaf(av[i], w.y, acc[i][1]);
                acc[i][2] = fmaf(av[i], w.z, acc[i][2]);
                acc[i][3] = fmaf(av[i], w.w, acc[i][3]);
            }
        }
    }
    // write q to global + qT (transposed) to LDS
    #pragma unroll
    for (int i = 0; i < 8; ++i) {
        int g = t * PER_TYPE + n0 + eg * 8 + i;
        *(float4*)(q_out + (size_t)g * UD + c4) =
            make_float4(acc[i][0], acc[i][1], acc[i][2], acc[i][3]);
    }
    #pragma unroll
    for (int j = 0; j < 4; ++j) {
        float4 lo = make_float4(acc[0][j], acc[1][j], acc[2][j], acc[3][j]);
        float4 hi = make_float4(acc[4][j], acc[5][j], acc[6][j], acc[7][j]);
        *(float4*)(&qT[(c4 + j) * XT_STRIDE + eg * 8]) = lo;
        *(float4*)(&qT[(c4 + j) * XT_STRIDE + eg * 8 + 4]) = hi;
    }
    __syncthreads();

    // phase 2: qk[ent][u] = sum_v qT[v][ent] * kT[t][v][u]
    #pragma unroll
    for (int i = 0; i < 8; ++i)
        #pragma unroll
        for (int j = 0; j < 4; ++j) acc[i][j] = 0.f;
    {
        const float* kw = kT + t * UD * UD;
        for (int v = 0; v < UD; ++v) {
            float4 w = *(const float4*)(kw + v * UD + c4);
            const float* qr = &qT[v * XT_STRIDE + eg * 8];
            float4 a0 = *(const float4*)(qr);
            float4 a1 = *(const float4*)(qr + 4);
            float av[8] = {a0.x, a0.y, a0.z, a0.w, a1.x, a1.y, a1.z, a1.w};
            #pragma unroll
            for (int i = 0; i < 8; ++i) {
                acc[i][0] = fmaf(av[i], w.x, acc[i][0]);
                acc[i][1] = fmaf(av[i], w.y, acc[i][1]);
                acc[i][2] = fmaf(av[i], w.z, acc[i][2]);
                acc[i][3] = fmaf(av[i], w.w, acc[i][3]);
            }
        }
    }
    #pragma unroll
    for (int i = 0; i < 8; ++i) {
        int g = t * PER_TYPE + n0 + eg * 8 + i;
        *(float4*)(qk_out + (size_t)g * UD + c4) =
            make_float4(acc[i][0], acc[i][1], acc[i][2], acc[i][3]);
    }
}

// ---------------- raw[n][h] = hist[idx[n]][h] . qk[n]  + per-(t,h) atomicMax --------
__global__ __launch_bounds__(256) void raw_kernel(
    const float* __restrict__ hist, const int* __restrict__ idx,
    const float* __restrict__ qk, float* __restrict__ raw,
    unsigned* __restrict__ Mbits)
{
    __shared__ int srow[32];
    int tx = threadIdx.x;
    int bn = blockIdx.x;     // 0..255 -> 32 entities
    int t  = blockIdx.y;
    int n0 = bn * 32;
    if (tx < 32) srow[tx] = idx[t * PER_TYPE + n0 + tx];
    __syncthreads();
    int sub = tx & 7;    // 16-float chunk of the 128-dim dot
    int hh  = tx >> 3;   // 0..31
    float vmax = -INFINITY;
    for (int ei = 0; ei < 32; ++ei) {
        int g = t * PER_TYPE + n0 + ei;
        const float* qr = qk + (size_t)g * UD + sub * 16;
        float4 q0 = *(const float4*)(qr);
        float4 q1 = *(const float4*)(qr + 4);
        float4 q2 = *(const float4*)(qr + 8);
        float4 q3 = *(const float4*)(qr + 12);
        const float* hr = hist + ((size_t)srow[ei] * HIST + hh) * UD + sub * 16;
        float4 h0 = *(const float4*)(hr);
        float4 h1 = *(const float4*)(hr + 4);
        float4 h2 = *(const float4*)(hr + 8);
        float4 h3 = *(const float4*)(hr + 12);
        float a = q0.x * h0.x + q0.y * h0.y + q0.z * h0.z + q0.w * h0.w;
        a = fmaf(q1.x, h1.x, fmaf(q1.y, h1.y, fmaf(q1.z, h1.z, fmaf(q1.w, h1.w, a))));
        a = fmaf(q2.x, h2.x, fmaf(q2.y, h2.y, fmaf(q2.z, h2.z, fmaf(q2.w, h2.w, a))));
        a = fmaf(q3.x, h3.x, fmaf(q3.y, h3.y, fmaf(q3.z, h3.z, fmaf(q3.w, h3.w, a))));
        a += __shfl_xor(a, 1);
        a += __shfl_xor(a, 2);
        a += __shfl_xor(a, 4);
        vmax = fmaxf(vmax, a);
        if (sub == 0) raw[(size_t)g * HIST + hh] = a;
    }
    if (sub == 0) atomicMax(&Mbits[t * HIST + hh], fkey(vmax));
}

// ---------------- S[t][h] = sum_n exp(raw - M) --------------------------------------
__global__ __launch_bounds__(256) void sum_kernel(
    const float* __restrict__ raw, const unsigned* __restrict__ Mbits,
    float* __restrict__ S)
{
    __shared__ float red[8][32];
    int tx = threadIdx.x;
    int c = blockIdx.x;    // 0..31 -> 256 entities
    int t = blockIdx.y;
    int hh = tx & 31;
    int nsl = tx >> 5;     // 0..7
    float M = funkey(Mbits[t * HIST + hh]);
    float s = 0.f;
    for (int i = 0; i < 32; ++i) {
        int n = c * 256 + i * 8 + nsl;
        float r = raw[((size_t)t * PER_TYPE + n) * HIST + hh];
        float e = r - M;
        if (e > -85.f) s += expf(e);   // below -85 exp underflows to ~0 anyway
    }
    red[nsl][hh] = s;
    __syncthreads();
    if (tx < 32) {
        float tot = 0.f;
        #pragma unroll
        for (int k = 0; k < 8; ++k) tot += red[k][tx];
        atomicAdd(&S[t * HIST + tx], tot);
    }
}

// ---------------- out: fast path out=q; slow path gather active h rows --------------
__global__ __launch_bounds__(256) void out_kernel(
    const float* __restrict__ hist, const int* __restrict__ idx,
    const float* __restrict__ q, const float* __restrict__ raw,
    const unsigned* __restrict__ Mbits, const float* __restrict__ S,
    const float* __restrict__ wvf, float* __restrict__ out)
{
    __shared__ float shbar[4][UD];
    int tx = threadIdx.x;
    int wave = tx >> 6;
    int lane = tx & 63;
    int g = blockIdx.x * 4 + wave;   // global entity 0..32767
    int t = g >> 13;                 // /8192
    float w = 0.f;
    if (lane < 32) {
        float r = raw[(size_t)g * HIST + lane];
        float M = funkey(Mbits[t * HIST + lane]);
        float e = r - M;
        if (e > -75.f) w = expf(e) / S[t * HIST + lane];  // skipped terms < 3e-33
    }
    unsigned long long act = __ballot(w != 0.f);
    int u2 = lane * 2;
    float2 qv = *(const float2*)(q + (size_t)g * UD + u2);
    float2 o;
    if (act == 0ull) {
        o = qv;  // all attention weights exactly 0 -> relu(0) + q
    } else {
        int row = idx[g];
        float2 hb = make_float2(0.f, 0.f);
        unsigned long long m = act;
        while (m) {
            int hh = __ffsll(m) - 1;
            m &= m - 1;
            float wv = __shfl(w, hh);
            float2 hv = *(const float2*)(hist + ((size_t)row * HIST + hh) * UD + u2);
            hb.x = fmaf(wv, hv.x, hb.x);
            hb.y = fmaf(wv, hv.y, hb.y);
        }
        // wave-local LDS round trip (no barrier needed within one wave)
        shbar[wave][u2] = hb.x;
        shbar[wave][u2 + 1] = hb.y;
        float2 a = make_float2(0.f, 0.f);
        const float* wt = wvf + t * UD * UD;
        for (int e = 0; e < UD; ++e) {
            float hbe = shbar[wave][e];
            float2 wr = *(const float2*)(wt + e * UD + u2);
            a.x = fmaf(hbe, wr.x, a.x);
            a.y = fmaf(hbe, wr.y, a.y);
        }
        o.x = fmaxf(a.x, 0.f) + qv.x;
        o.y = fmaxf(a.y, 0.f) + qv.y;
    }
    *(float2*)(out + (size_t)g * UD + u2) = o;
}

extern "C" void kernel_launch(void* const* d_in, const int* in_sizes, int n_in,
                              void* d_out, int out_size, void* d_ws, size_t ws_size,
                              hipStream_t stream) {
    const float* x    = (const float*)d_in[0];
    const float* hist = (const float*)d_in[1];
    const int*   idx  = (const int*)d_in[2];
    const float* q_w  = (const float*)d_in[3];
    const float* k_w  = (const float*)d_in[4];
    const float* v_w  = (const float*)d_in[5];
    const float* fc_w = (const float*)d_in[6];
    float* out = (float*)d_out;

    float* ws = (float*)d_ws;
    float* q     = ws;
    float* qk    = ws + 4194304;
    float* raw   = ws + 8388608;
    unsigned* Mb = (unsigned*)(ws + 9437184);
    float* S     = ws + 9437312;
    float* kT    = ws + 9437440;
    float* wvf   = ws + 9502976;

    prep_kernel<<<dim3(128, 4), 128, 0, stream>>>(k_w, v_w, fc_w, kT, wvf, Mb, S);
    qqk_kernel<<<dim3(128, 4), 256, 0, stream>>>(x, idx, q_w, kT, q, qk);
    raw_kernel<<<dim3(256, 4), 256, 0, stream>>>(hist, idx, qk, raw, Mb);
    sum_kernel<<<dim3(32, 4), 256, 0, stream>>>(raw, Mb, S);
    out_kernel<<<8192, 256, 0, stream>>>(hist, idx, q, raw, Mb, S, wvf, out);
}

// Round 2
// 747.102 us; speedup vs baseline: 1.0010x; 1.0010x over previous
//
#include <hip/hip_runtime.h>
#include <math.h>

#define NPTS 32768
#define NTYPES 4
#define PER_TYPE 8192
#define HIST 32
#define UD 128
#define XT_STRIDE 68   // pad 128-row tiles: 68*4B=272B row pitch, 16B-aligned, breaks pow2 bank stride

// ws layout (float offsets):
//   q     [32768][128]      @ 0
//   qk    [32768][128]      @ 4194304
//   raw   [32768][32]       @ 8388608
//   Mbits [128] (uint)      @ 9437184
//   S     [128]             @ 9437312
//   kT    [4][128][128]     @ 9437440   (k_w transposed per type)
//   wvf   [4][128][128]     @ 9502976   (v_w @ fc_w per type)
// total 9568512 floats = 38.3 MB

__device__ __forceinline__ unsigned fkey(float x) {
    unsigned b = __float_as_uint(x);
    return (b & 0x80000000u) ? ~b : (b | 0x80000000u);
}
__device__ __forceinline__ float funkey(unsigned k) {
    unsigned b = (k & 0x80000000u) ? (k & 0x7fffffffu) : ~k;
    return __uint_as_float(b);
}

// ---------------- prep: kT = k_w^T, wvf = v_w @ fc_w, zero softmax stats -------------
__global__ __launch_bounds__(128) void prep_kernel(
    const float* __restrict__ k_w, const float* __restrict__ v_w,
    const float* __restrict__ fc_w, float* __restrict__ kT,
    float* __restrict__ wvf, unsigned* __restrict__ Mbits, float* __restrict__ S)
{
    int r = blockIdx.x;   // 0..127 (row of output)
    int t = blockIdx.y;   // type
    int u = threadIdx.x;  // 0..127 (col)
    // kT[t][r][u] = k_w[t][u][r]
    kT[(t * UD + r) * UD + u] = k_w[(t * UD + u) * UD + r];
    // wvf[t][r][u] = sum_m v_w[t][r][m] * fc_w[t][m][u]
    float acc = 0.f;
    const float* vrow = v_w + (t * UD + r) * UD;
    const float* fb = fc_w + t * UD * UD;
    #pragma unroll 8
    for (int m = 0; m < UD; ++m)
        acc = fmaf(vrow[m], fb[m * UD + u], acc);
    wvf[(t * UD + r) * UD + u] = acc;
    if (r == 0 && t == 0) { Mbits[u] = 0u; S[u] = 0.f; }
}

// ---------------- q = x[idx] @ q_w ; qk = q @ k_w^T  (per 64-entity tile) ------------
__global__ __launch_bounds__(256) void qqk_kernel(
    const float* __restrict__ x, const int* __restrict__ idx,
    const float* __restrict__ q_w, const float* __restrict__ kT,
    float* __restrict__ q_out, float* __restrict__ qk_out)
{
    __shared__ float xT[UD * XT_STRIDE];  // [e][ent], padded
    __shared__ float qT[UD * XT_STRIDE];  // [c][ent], padded
    __shared__ int srow[64];
    int tx = threadIdx.x;
    int bn = blockIdx.x;      // 0..127 -> 64 entities
    int t  = blockIdx.y;
    int n0 = bn * 64;

    if (tx < 64) srow[tx] = idx[t * PER_TYPE + n0 + tx];
    __syncthreads();

    // load x transposed into LDS: xT[e][ent]
    {
        int e = tx & 127;
        int half = tx >> 7;
        for (int i = 0; i < 32; ++i) {
            int ent = half * 32 + i;
            xT[e * XT_STRIDE + ent] = x[(size_t)srow[ent] * UD + e];
        }
    }
    __syncthreads();

    const int c4 = (tx & 31) * 4;  // 4 output cols
    const int eg = tx >> 5;        // 0..7 -> 8 entities eg*8..eg*8+7
    float acc[8][4];

    // phase 1: q[ent][c] = sum_e xT[e][ent] * q_w[e][c]
    #pragma unroll
    for (int i = 0; i < 8; ++i)
        #pragma unroll
        for (int j = 0; j < 4; ++j) acc[i][j] = 0.f;
    {
        const float* qw = q_w + t * UD * UD;
        for (int e = 0; e < UD; ++e) {
            float4 w = *(const float4*)(qw + e * UD + c4);
            const float* xr = &xT[e * XT_STRIDE + eg * 8];
            float4 a0 = *(const float4*)(xr);
            float4 a1 = *(const float4*)(xr + 4);
            float av[8] = {a0.x, a0.y, a0.z, a0.w, a1.x, a1.y, a1.z, a1.w};
            #pragma unroll
            for (int i = 0; i < 8; ++i) {
                acc[i][0] = fmaf(av[i], w.x, acc[i][0]);
                acc[i][1] = fmaf(av[i], w.y, acc[i][1]);
                acc[i][2] = fmaf(av[i], w.z, acc[i][2]);
                acc[i][3] = fmaf(av[i], w.w, acc[i][3]);
            }
        }
    }
    // write q to global + qT (transposed) to LDS
    #pragma unroll
    for (int i = 0; i < 8; ++i) {
        int g = t * PER_TYPE + n0 + eg * 8 + i;
        *(float4*)(q_out + (size_t)g * UD + c4) =
            make_float4(acc[i][0], acc[i][1], acc[i][2], acc[i][3]);
    }
    #pragma unroll
    for (int j = 0; j < 4; ++j) {
        float4 lo = make_float4(acc[0][j], acc[1][j], acc[2][j], acc[3][j]);
        float4 hi = make_float4(acc[4][j], acc[5][j], acc[6][j], acc[7][j]);
        *(float4*)(&qT[(c4 + j) * XT_STRIDE + eg * 8]) = lo;
        *(float4*)(&qT[(c4 + j) * XT_STRIDE + eg * 8 + 4]) = hi;
    }
    __syncthreads();

    // phase 2: qk[ent][u] = sum_v qT[v][ent] * kT[t][v][u]
    #pragma unroll
    for (int i = 0; i < 8; ++i)
        #pragma unroll
        for (int j = 0; j < 4; ++j) acc[i][j] = 0.f;
    {
        const float* kw = kT + t * UD * UD;
        for (int v = 0; v < UD; ++v) {
            float4 w = *(const float4*)(kw + v * UD + c4);
            const float* qr = &qT[v * XT_STRIDE + eg * 8];
            float4 a0 = *(const float4*)(qr);
            float4 a1 = *(const float4*)(qr + 4);
            float av[8] = {a0.x, a0.y, a0.z, a0.w, a1.x, a1.y, a1.z, a1.w};
            #pragma unroll
            for (int i = 0; i < 8; ++i) {
                acc[i][0] = fmaf(av[i], w.x, acc[i][0]);
                acc[i][1] = fmaf(av[i], w.y, acc[i][1]);
                acc[i][2] = fmaf(av[i], w.z, acc[i][2]);
                acc[i][3] = fmaf(av[i], w.w, acc[i][3]);
            }
        }
    }
    #pragma unroll
    for (int i = 0; i < 8; ++i) {
        int g = t * PER_TYPE + n0 + eg * 8 + i;
        *(float4*)(qk_out + (size_t)g * UD + c4) =
            make_float4(acc[i][0], acc[i][1], acc[i][2], acc[i][3]);
    }
}

// ---------------- raw[n][h] = hist[idx[n]][h] . qk[n]  + per-(t,h) max --------------
// v2: 16 entities/block (2048 blocks), qk staged in LDS, 32 floats/lane ->
// 8 independent dwordx4 hist loads in flight per lane, 2-level shuffle reduce,
// block-level LDS max reduction before the global atomic.
__global__ __launch_bounds__(256) void raw_kernel(
    const float* __restrict__ hist, const int* __restrict__ idx,
    const float* __restrict__ qk, float* __restrict__ raw,
    unsigned* __restrict__ Mbits)
{
    __shared__ int srow[16];
    __shared__ float sqk[16 * UD];
    __shared__ unsigned smax[HIST];
    int tx = threadIdx.x;
    int bn = blockIdx.x;       // 0..511 -> 16 entities
    int t  = blockIdx.y;
    int n0 = bn * 16;
    if (tx < 16) srow[tx] = idx[t * PER_TYPE + n0 + tx];
    if (tx < HIST) smax[tx] = 0u;
    {   // stage 16 qk rows (8 KB) into LDS, coalesced
        int e = tx >> 4;          // entity 0..15
        int c = (tx & 15) * 8;    // col 0..120
        const float* src = qk + ((size_t)(t * PER_TYPE + n0 + e)) * UD + c;
        float4 a = *(const float4*)(src);
        float4 b = *(const float4*)(src + 4);
        *(float4*)(&sqk[e * UD + c]) = a;
        *(float4*)(&sqk[e * UD + c + 4]) = b;
    }
    __syncthreads();

    int sub = tx & 3;          // which 32-float chunk of the 128-dot
    int hh  = (tx >> 2) & 31;  // history row
    int eh  = tx >> 7;         // 0/1: which entity of the current pair
    float vmax = -INFINITY;
    for (int j = 0; j < 8; ++j) {
        int ei = j * 2 + eh;
        int g  = t * PER_TYPE + n0 + ei;
        const float* hr = hist + ((size_t)srow[ei] * HIST + hh) * UD + sub * 32;
        // 8 independent global loads issued before any use
        float4 h0 = *(const float4*)(hr);
        float4 h1 = *(const float4*)(hr + 4);
        float4 h2 = *(const float4*)(hr + 8);
        float4 h3 = *(const float4*)(hr + 12);
        float4 h4 = *(const float4*)(hr + 16);
        float4 h5 = *(const float4*)(hr + 20);
        float4 h6 = *(const float4*)(hr + 24);
        float4 h7 = *(const float4*)(hr + 28);
        const float* qr = &sqk[ei * UD + sub * 32];
        float4 q0 = *(const float4*)(qr);
        float4 q1 = *(const float4*)(qr + 4);
        float4 q2 = *(const float4*)(qr + 8);
        float4 q3 = *(const float4*)(qr + 12);
        float4 q4 = *(const float4*)(qr + 16);
        float4 q5 = *(const float4*)(qr + 20);
        float4 q6 = *(const float4*)(qr + 24);
        float4 q7 = *(const float4*)(qr + 28);
        // 4 independent partial chains
        float p0 = q0.x * h0.x + q0.y * h0.y + q0.z * h0.z + q0.w * h0.w;
        float p1 = q1.x * h1.x + q1.y * h1.y + q1.z * h1.z + q1.w * h1.w;
        float p2 = q2.x * h2.x + q2.y * h2.y + q2.z * h2.z + q2.w * h2.w;
        float p3 = q3.x * h3.x + q3.y * h3.y + q3.z * h3.z + q3.w * h3.w;
        p0 = fmaf(q4.x, h4.x, fmaf(q4.y, h4.y, fmaf(q4.z, h4.z, fmaf(q4.w, h4.w, p0))));
        p1 = fmaf(q5.x, h5.x, fmaf(q5.y, h5.y, fmaf(q5.z, h5.z, fmaf(q5.w, h5.w, p1))));
        p2 = fmaf(q6.x, h6.x, fmaf(q6.y, h6.y, fmaf(q6.z, h6.z, fmaf(q6.w, h6.w, p2))));
        p3 = fmaf(q7.x, h7.x, fmaf(q7.y, h7.y, fmaf(q7.z, h7.z, fmaf(q7.w, h7.w, p3))));
        float a = (p0 + p1) + (p2 + p3);
        a += __shfl_xor(a, 1);
        a += __shfl_xor(a, 2);
        vmax = fmaxf(vmax, a);
        if (sub == 0) raw[(size_t)g * HIST + hh] = a;
    }
    if (sub == 0) atomicMax(&smax[hh], fkey(vmax));   // LDS atomic, cheap
    __syncthreads();
    if (tx < HIST) atomicMax(&Mbits[t * HIST + tx], smax[tx]);
}

// ---------------- S[t][h] = sum_n exp(raw - M) --------------------------------------
__global__ __launch_bounds__(256) void sum_kernel(
    const float* __restrict__ raw, const unsigned* __restrict__ Mbits,
    float* __restrict__ S)
{
    __shared__ float red[8][32];
    int tx = threadIdx.x;
    int c = blockIdx.x;    // 0..31 -> 256 entities
    int t = blockIdx.y;
    int hh = tx & 31;
    int nsl = tx >> 5;     // 0..7
    float M = funkey(Mbits[t * HIST + hh]);
    float s = 0.f;
    for (int i = 0; i < 32; ++i) {
        int n = c * 256 + i * 8 + nsl;
        float r = raw[((size_t)t * PER_TYPE + n) * HIST + hh];
        float e = r - M;
        if (e > -85.f) s += expf(e);   // below -85 exp underflows to ~0 anyway
    }
    red[nsl][hh] = s;
    __syncthreads();
    if (tx < 32) {
        float tot = 0.f;
        #pragma unroll
        for (int k = 0; k < 8; ++k) tot += red[k][tx];
        atomicAdd(&S[t * HIST + tx], tot);
    }
}

// ---------------- out: fast path out=q; slow path gather active h rows --------------
__global__ __launch_bounds__(256) void out_kernel(
    const float* __restrict__ hist, const int* __restrict__ idx,
    const float* __restrict__ q, const float* __restrict__ raw,
    const unsigned* __restrict__ Mbits, const float* __restrict__ S,
    const float* __restrict__ wvf, float* __restrict__ out)
{
    __shared__ float shbar[4][UD];
    int tx = threadIdx.x;
    int wave = tx >> 6;
    int lane = tx & 63;
    int g = blockIdx.x * 4 + wave;   // global entity 0..32767
    int t = g >> 13;                 // /8192
    float w = 0.f;
    if (lane < 32) {
        float r = raw[(size_t)g * HIST + lane];
        float M = funkey(Mbits[t * HIST + lane]);
        float e = r - M;
        if (e > -75.f) w = expf(e) / S[t * HIST + lane];  // skipped terms < 3e-33
    }
    unsigned long long act = __ballot(w != 0.f);
    int u2 = lane * 2;
    float2 qv = *(const float2*)(q + (size_t)g * UD + u2);
    float2 o;
    if (act == 0ull) {
        o = qv;  // all attention weights exactly 0 -> relu(0) + q
    } else {
        int row = idx[g];
        float2 hb = make_float2(0.f, 0.f);
        unsigned long long m = act;
        while (m) {
            int hh = __ffsll(m) - 1;
            m &= m - 1;
            float wv = __shfl(w, hh);
            float2 hv = *(const float2*)(hist + ((size_t)row * HIST + hh) * UD + u2);
            hb.x = fmaf(wv, hv.x, hb.x);
            hb.y = fmaf(wv, hv.y, hb.y);
        }
        // wave-local LDS round trip (no barrier needed within one wave)
        shbar[wave][u2] = hb.x;
        shbar[wave][u2 + 1] = hb.y;
        float2 a = make_float2(0.f, 0.f);
        const float* wt = wvf + t * UD * UD;
        for (int e = 0; e < UD; ++e) {
            float hbe = shbar[wave][e];
            float2 wr = *(const float2*)(wt + e * UD + u2);
            a.x = fmaf(hbe, wr.x, a.x);
            a.y = fmaf(hbe, wr.y, a.y);
        }
        o.x = fmaxf(a.x, 0.f) + qv.x;
        o.y = fmaxf(a.y, 0.f) + qv.y;
    }
    *(float2*)(out + (size_t)g * UD + u2) = o;
}

extern "C" void kernel_launch(void* const* d_in, const int* in_sizes, int n_in,
                              void* d_out, int out_size, void* d_ws, size_t ws_size,
                              hipStream_t stream) {
    const float* x    = (const float*)d_in[0];
    const float* hist = (const float*)d_in[1];
    const int*   idx  = (const int*)d_in[2];
    const float* q_w  = (const float*)d_in[3];
    const float* k_w  = (const float*)d_in[4];
    const float* v_w  = (const float*)d_in[5];
    const float* fc_w = (const float*)d_in[6];
    float* out = (float*)d_out;

    float* ws = (float*)d_ws;
    float* q     = ws;
    float* qk    = ws + 4194304;
    float* raw   = ws + 8388608;
    unsigned* Mb = (unsigned*)(ws + 9437184);
    float* S     = ws + 9437312;
    float* kT    = ws + 9437440;
    float* wvf   = ws + 9502976;

    prep_kernel<<<dim3(128, 4), 128, 0, stream>>>(k_w, v_w, fc_w, kT, wvf, Mb, S);
    qqk_kernel<<<dim3(128, 4), 256, 0, stream>>>(x, idx, q_w, kT, q, qk);
    raw_kernel<<<dim3(512, 4), 256, 0, stream>>>(hist, idx, qk, raw, Mb);
    sum_kernel<<<dim3(32, 4), 256, 0, stream>>>(raw, Mb, S);
    out_kernel<<<8192, 256, 0, stream>>>(hist, idx, q, raw, Mb, S, wvf, out);
}